// Round 2
// baseline (791.641 us; speedup 1.0000x reference)
//
#include <hip/hip_runtime.h>
#include <hip/hip_bf16.h>
#include <cstdint>
#include <cstddef>

typedef __hip_bfloat16 bf16;
typedef __attribute__((ext_vector_type(8))) short s8v;   // 8 bf16 (4 VGPRs) MFMA A/B frag
typedef __attribute__((ext_vector_type(4))) float f4v;   // MFMA C/D frag

#define NH 32
#define NKV 8
#define HD 128
#define BB 2
#define SS 2048
#define HH 4096
#define QKVO 6144
#define MM 4096

// ---------- async global->LDS (16B per lane) ----------
__device__ __forceinline__ void gld_lds16(const void* g, void* l) {
    __builtin_amdgcn_global_load_lds(
        (const __attribute__((address_space(1))) void*)g,
        (__attribute__((address_space(3))) void*)l, 16, 0, 0);
}

#define MFMA_BF16(a, b, c) __builtin_amdgcn_mfma_f32_16x16x32_bf16((a), (b), (c), 0, 0, 0)

// ---------- f32 -> bf16 convert, 8 elems/thread ----------
struct alignas(16) bf16x8s { bf16 v[8]; };
__global__ __launch_bounds__(256) void conv_kernel(const float* __restrict__ in,
                                                   bf16* __restrict__ out, int n8) {
    int i = blockIdx.x * 256 + threadIdx.x;
    if (i >= n8) return;
    const float4* in4 = (const float4*)in;
    float4 a = in4[i * 2];
    float4 b = in4[i * 2 + 1];
    bf16x8s p;
    p.v[0] = __float2bfloat16(a.x); p.v[1] = __float2bfloat16(a.y);
    p.v[2] = __float2bfloat16(a.z); p.v[3] = __float2bfloat16(a.w);
    p.v[4] = __float2bfloat16(b.x); p.v[5] = __float2bfloat16(b.y);
    p.v[6] = __float2bfloat16(b.z); p.v[7] = __float2bfloat16(b.w);
    *(bf16x8s*)(out + (size_t)i * 8) = p;
}

// =====================================================================
// 256x256-tile 8-phase GEMM, deep-prefetch variant.
// 8 waves (2M x 4N), BK=64, 2x double-buffered LDS (128 KiB).
// Key change vs previous round: staging for tile t+2 goes INTO buf p
// (the buffer being read by tile t) region-by-region as each region's
// reads retire block-wide:
//   region read-complete:  AQ0,BS0 after P1 | BS1 after P2 | AQ1 after P3
//   stage (t+2):           P2: AQ0+BS0      | P3: BS1       | P4: AQ1
// Issue->drain distance = 6-7 phases (was 2-3) -> HBM latency hidden.
// Per-wave load ledger (2 loads per 16KiB region, uniform across waves):
//   steady outstanding after each wait = {P1:12->10(+0), P2:+4 ->12,
//   P3:+2 (no wait), P4:+2 =16 ->12}. Waits drain exactly the loads the
//   NEXT phase reads; each wait sits before the barrier preceding those
//   reads (vmcnt is per-wave; vmcnt+barrier = block-wide guarantee).
// LDS slot swizzle unchanged (T2, rule #21): linear dest + inverse-
// swizzled global source + swizzled ds_read.
// =====================================================================
__device__ __forceinline__ void stage8(const bf16* __restrict__ g, int ldg, int kt,
                                       int r0, bf16* lbase, int lane) {
    // one wave stages 8 rows (r0 8-aligned): lane covers 16B of row r0+(lane>>3)
    int row = r0 + (lane >> 3);
    int slot = (lane & 7) ^ ((lane >> 3) & 7);      // inverse swizzle on source
    gld_lds16(g + (size_t)row * ldg + kt * 64 + slot * 8,
              (char*)lbase + r0 * 128 + lane * 16); // linear dest
}

template <typename OutT>
__global__ __launch_bounds__(512, 2) void gemm_bt256(const bf16* __restrict__ A,
                                                     const bf16* __restrict__ Bm,
                                                     OutT* __restrict__ C,
                                                     int M, int N, int K) {
    __shared__ bf16 sA[2][256 * 64];
    __shared__ bf16 sB[2][256 * 64];
    const int tid = threadIdx.x;
    const int lane = tid & 63;
    const int wave = tid >> 6;                 // 0..7
    const int l15 = lane & 15, quad = lane >> 4;
    const int wm = wave >> 2;                  // 0..1 -> 128 M-rows each
    const int wn = wave & 3;                   // 0..3 -> 64 N-cols each

    // XCD-aware block swizzle (nwg % 8 == 0 for both call sites)
    const int nbn = N >> 8;
    const int nwg = (M >> 8) * nbn;
    const int orig = blockIdx.y * gridDim.x + blockIdx.x;
    const int cpx = nwg >> 3;
    const int swz = (orig & 7) * cpx + (orig >> 3);
    const int bm = swz / nbn, bn = swz % nbn;

    const bf16* Ab = A + (size_t)bm * 256 * K;
    const bf16* Bb = Bm + (size_t)bn * 256 * K;
    const int NT = K >> 6;                     // K-tiles of 64

    // per-wave region row bases
    const int aq0 = wave * 8;                              // A quarter rows (+0/+128; +64 for Q1)
    const int bs0 = (wave >> 2) * 64 + (wave & 3) * 8;     // B stripe rows (+0/+128; +32 for S1)

    // swizzled ds_read addressing: byte = row*128 + ((k*4+quad)^(l15&7))*16
    const int soff0 = (quad ^ (l15 & 7)) << 4;
    const int ra  = (wm * 128 + l15) * 128;    // A byte row base
    const int rbb = (wn * 64 + l15) * 128;     // B byte row base
#define LDA(p, m, k) (*(const s8v*)((const char*)sA[p] + ra  + (m) * 2048 + (soff0 ^ ((k) << 6))))
#define LDB(p, n, k) (*(const s8v*)((const char*)sB[p] + rbb + (n) * 2048 + (soff0 ^ ((k) << 6))))

    f4v acc[8][4] = {};
    s8v a[4][2], b0[2][2], b1[2][2];

    // ---- prologue: tiles 0 and 1, FIFO order AQ0,BS0,BS1,AQ1 per tile ----
#pragma unroll
    for (int u = 0; u < 2; ++u) {
        stage8(Ab, K, u, aq0,        sA[u], lane);
        stage8(Ab, K, u, aq0 + 128,  sA[u], lane);
        stage8(Bb, K, u, bs0,        sB[u], lane);
        stage8(Bb, K, u, bs0 + 128,  sB[u], lane);
        stage8(Bb, K, u, bs0 + 32,   sB[u], lane);
        stage8(Bb, K, u, bs0 + 160,  sB[u], lane);
        stage8(Ab, K, u, aq0 + 64,   sA[u], lane);
        stage8(Ab, K, u, aq0 + 192,  sA[u], lane);
    }
    asm volatile("s_waitcnt vmcnt(12)" ::: "memory");   // AQ0(0)+BS0(0) landed
    __builtin_amdgcn_s_barrier();

    for (int t = 0; t < NT; ++t) {
        const int p = t & 1;
        const int kt2 = t + 2;
        const bool s2 = kt2 < NT;
        // ---------------- P1: acc[0..3][0..1], reads AQ0+BS0 ----------------
#pragma unroll
        for (int m = 0; m < 4; ++m) { a[m][0] = LDA(p, m, 0); a[m][1] = LDA(p, m, 1); }
#pragma unroll
        for (int n = 0; n < 2; ++n) { b0[n][0] = LDB(p, n, 0); b0[n][1] = LDB(p, n, 1); }
        asm volatile("s_waitcnt lgkmcnt(8)" ::: "memory");
        __builtin_amdgcn_s_barrier();
        asm volatile("s_waitcnt lgkmcnt(0)" ::: "memory");
        __builtin_amdgcn_sched_barrier(0);
        __builtin_amdgcn_s_setprio(1);
#pragma unroll
        for (int m = 0; m < 4; ++m)
#pragma unroll
            for (int n = 0; n < 2; ++n) {
                acc[m][n] = MFMA_BF16(a[m][0], b0[n][0], acc[m][n]);
                acc[m][n] = MFMA_BF16(a[m][1], b0[n][1], acc[m][n]);
            }
        __builtin_amdgcn_s_setprio(0);
        // wait for BS1(t) (read next phase); drained loads issued 6 phases ago
        if (t + 1 < NT) { asm volatile("s_waitcnt vmcnt(10)" ::: "memory"); }
        else            { asm volatile("s_waitcnt vmcnt(2)"  ::: "memory"); }
        __builtin_amdgcn_s_barrier();
        // ---------------- P2: acc[0..3][2..3], reads BS1; stage AQ0+BS0(t+2) ----------------
#pragma unroll
        for (int n = 0; n < 2; ++n) { b1[n][0] = LDB(p, n + 2, 0); b1[n][1] = LDB(p, n + 2, 1); }
        if (s2) {
            stage8(Ab, K, kt2, aq0,       sA[p], lane);
            stage8(Ab, K, kt2, aq0 + 128, sA[p], lane);
            stage8(Bb, K, kt2, bs0,       sB[p], lane);
            stage8(Bb, K, kt2, bs0 + 128, sB[p], lane);
        }
        __builtin_amdgcn_s_barrier();
        asm volatile("s_waitcnt lgkmcnt(0)" ::: "memory");
        __builtin_amdgcn_sched_barrier(0);
        __builtin_amdgcn_s_setprio(1);
#pragma unroll
        for (int m = 0; m < 4; ++m)
#pragma unroll
            for (int n = 0; n < 2; ++n) {
                acc[m][n + 2] = MFMA_BF16(a[m][0], b1[n][0], acc[m][n + 2]);
                acc[m][n + 2] = MFMA_BF16(a[m][1], b1[n][1], acc[m][n + 2]);
            }
        __builtin_amdgcn_s_setprio(0);
        // wait for AQ1(t) (read next phase)
        if (s2)             { asm volatile("s_waitcnt vmcnt(12)" ::: "memory"); }
        else if (t + 1 < NT){ asm volatile("s_waitcnt vmcnt(8)"  ::: "memory"); }
        else                { asm volatile("s_waitcnt vmcnt(0)"  ::: "memory"); }
        __builtin_amdgcn_s_barrier();
        // ---------------- P3: acc[4..7][2..3], reads AQ1; stage BS1(t+2) ----------------
#pragma unroll
        for (int m = 0; m < 4; ++m) { a[m][0] = LDA(p, m + 4, 0); a[m][1] = LDA(p, m + 4, 1); }
        if (s2) {
            stage8(Bb, K, kt2, bs0 + 32,  sB[p], lane);
            stage8(Bb, K, kt2, bs0 + 160, sB[p], lane);
        }
        __builtin_amdgcn_s_barrier();
        asm volatile("s_waitcnt lgkmcnt(0)" ::: "memory");
        __builtin_amdgcn_sched_barrier(0);
        __builtin_amdgcn_s_setprio(1);
#pragma unroll
        for (int m = 0; m < 4; ++m)
#pragma unroll
            for (int n = 0; n < 2; ++n) {
                acc[m + 4][n + 2] = MFMA_BF16(a[m][0], b1[n][0], acc[m + 4][n + 2]);
                acc[m + 4][n + 2] = MFMA_BF16(a[m][1], b1[n][1], acc[m + 4][n + 2]);
            }
        __builtin_amdgcn_s_setprio(0);
        __builtin_amdgcn_s_barrier();
        // ---------------- P4: acc[4..7][0..1], no reads; stage AQ1(t+2) ----------------
        if (s2) {
            stage8(Ab, K, kt2, aq0 + 64,  sA[p], lane);
            stage8(Ab, K, kt2, aq0 + 192, sA[p], lane);
        }
        __builtin_amdgcn_s_setprio(1);
#pragma unroll
        for (int m = 0; m < 4; ++m)
#pragma unroll
            for (int n = 0; n < 2; ++n) {
                acc[m + 4][n] = MFMA_BF16(a[m][0], b0[n][0], acc[m + 4][n]);
                acc[m + 4][n] = MFMA_BF16(a[m][1], b0[n][1], acc[m + 4][n]);
            }
        __builtin_amdgcn_s_setprio(0);
        // wait for AQ0(t+1)+BS0(t+1) (read in next tile's P1)
        if (s2)              { asm volatile("s_waitcnt vmcnt(12)" ::: "memory"); }
        else if (t + 1 < NT) { asm volatile("s_waitcnt vmcnt(4)"  ::: "memory"); }
        __builtin_amdgcn_s_barrier();
    }
#undef LDA
#undef LDB

    // ---- epilogue ----
#pragma unroll
    for (int m = 0; m < 8; ++m)
#pragma unroll
        for (int n = 0; n < 4; ++n) {
            int r0 = bm * 256 + wm * 128 + m * 16 + quad * 4;
            int c0 = bn * 256 + wn * 64 + n * 16 + l15;
#pragma unroll
            for (int r = 0; r < 4; ++r) {
                float v = acc[m][n][r];
                if constexpr (sizeof(OutT) == 2)
                    C[(size_t)(r0 + r) * N + c0] = (OutT)__float2bfloat16(v);
                else
                    C[(size_t)(r0 + r) * N + c0] = (OutT)v;
            }
        }
}

// ---------- RMSNorm + RoPE for Q and K heads ----------
__global__ __launch_bounds__(128) void norm_rope_kernel(
    const bf16* __restrict__ qkv, const int* __restrict__ positions,
    const float* __restrict__ qw, const float* __restrict__ kw,
    bf16* __restrict__ qb, bf16* __restrict__ kb) {
    int rowid = blockIdx.x;   // 0..4095 (b*2048+s)
    int head = blockIdx.y;    // 0..39   (0..31 q, 32..39 k)
    int d = threadIdx.x;      // 0..127
    int b = rowid >> 11, s = rowid & 2047;
    bool isq = head < NH;
    int col = isq ? head * HD + d : NH * HD + (head - NH) * HD + d;
    float x = __bfloat162float(qkv[(size_t)rowid * QKVO + col]);

    __shared__ float sv[128];
    __shared__ float partial[2];
    float ss = x * x;
#pragma unroll
    for (int off = 32; off; off >>= 1) ss += __shfl_xor(ss, off, 64);
    if ((threadIdx.x & 63) == 0) partial[threadIdx.x >> 6] = ss;
    __syncthreads();
    float var = (partial[0] + partial[1]) * (1.0f / 128.0f);
    float w = isq ? qw[d] : kw[d];
    float xn = x * rsqrtf(var + 1e-6f) * w;
    sv[d] = xn;
    __syncthreads();

    float pos = (float)positions[s];
    float o;
    // inv_freq = 10000^(-i/64) = exp2(-i * log2(10000)/64), log2(10000)=13.2877123795
    if (d < 64) {
        float ang = pos * exp2f(-(float)d * 0.20762051f);
        float c, si; __sincosf(ang, &si, &c);
        o = xn * c - sv[d + 64] * si;
    } else {
        int i = d - 64;
        float ang = pos * exp2f(-(float)i * 0.20762051f);
        float c, si; __sincosf(ang, &si, &c);
        o = xn * c + sv[i] * si;
    }
    if (isq) o *= 0.08838834764831845f;  // 1/sqrt(128) folded into Q
    size_t oidx;
    if (isq) oidx = (((size_t)(b * NH + head) * SS + s) * HD + d);
    else     oidx = (((size_t)(b * NKV + (head - NH)) * SS + s) * HD + d);
    (isq ? qb : kb)[oidx] = __float2bfloat16(o);
}

// ---------- V transpose: qkv v-part [s][d] -> vt [b][kv][d][s] ----------
__global__ __launch_bounds__(256) void vtrans_kernel(const bf16* __restrict__ qkv,
                                                     bf16* __restrict__ vt) {
    int bh = blockIdx.z;           // b*8+hv
    int s0 = blockIdx.x * 32, d0 = blockIdx.y * 32;
    int b = bh >> 3, hv = bh & 7;
    __shared__ bf16 tile[32][33];
    int tx = threadIdx.x, ty = threadIdx.y;
    size_t colbase = (size_t)(NH + NKV) * HD + hv * HD + d0;  // v starts at col 5120
    for (int i = 0; i < 4; i++) {
        int s = s0 + ty + i * 8;
        tile[ty + i * 8][tx] = qkv[(size_t)(b * SS + s) * QKVO + colbase + tx];
    }
    __syncthreads();
    for (int i = 0; i < 4; i++) {
        int d = d0 + ty + i * 8;
        vt[((size_t)(bh * HD + d)) * SS + s0 + tx] = tile[tx][ty + i * 8];
    }
}

// ---------- causal flash attention ----------
// BQ=128, BK=64, 8 waves. No-max softmax: post-RMSNorm |score| <= sqrt(128),
// so exp(score) <= 8.2e4 and sum <= 1.7e8 -- safe in f32 without max
// subtraction. Work-balanced: block pi handles q-tiles {pi, 15-pi}.
__global__ __launch_bounds__(512, 4) void attn_kernel(
    const bf16* __restrict__ q, const bf16* __restrict__ k,
    const bf16* __restrict__ vt, bf16* __restrict__ out) {
    int pi = blockIdx.x;   // 0..7
    int h = blockIdx.y;
    int b = blockIdx.z;
    int hk = h >> 2;  // 4 q heads per kv head
    int tid = threadIdx.x, lane = tid & 63, wave = tid >> 6;  // wave 0..7
    int l15 = lane & 15, quad = lane >> 4;

    __shared__ bf16 sK[64][136];     // 272B stride: 2-way bank aliasing (free)
    __shared__ bf16 sVt[128][72];    // 144B stride
    __shared__ bf16 sP[8][16][72];   // per-wave P scratch

    const bf16* qg = q + ((size_t)(b * NH + h) * SS) * HD;
    const bf16* kg = k + ((size_t)(b * NKV + hk) * SS) * HD;
    const bf16* vg = vt + ((size_t)(b * NKV + hk) * HD) * SS;

    for (int half = 0; half < 2; half++) {
        int qt = half ? (15 - pi) : pi;
        int q0 = qt * 128;
        int qrow = q0 + wave * 16 + l15;
        s8v qf[4];
#pragma unroll
        for (int kc = 0; kc < 4; kc++)
            qf[kc] = *(const s8v*)(qg + (size_t)qrow * HD + kc * 32 + quad * 8);

        f4v o[8] = {};
        float lp[4] = {0.f, 0.f, 0.f, 0.f};   // per-lane partial row sums
        int qgrow[4];
#pragma unroll
        for (int r = 0; r < 4; r++) qgrow[r] = q0 + wave * 16 + quad * 4 + r;

        int nkt = 2 * qt + 2;  // causal: keys 0 .. q0+127, BK=64
        for (int kt = 0; kt < nkt; kt++) {
            int kbase = kt * 64;
            __syncthreads();  // prev iter's LDS reads done -> safe to restage
            // stage K tile [64 keys][128 d]
#pragma unroll
            for (int it = 0; it < 2; it++) {
                int c = tid + it * 512;
                int r = c >> 4, c8 = (c & 15) * 8;
                *(float4*)(&sK[r][c8]) =
                    *(const float4*)(kg + (size_t)(kbase + r) * HD + c8);
            }
            // stage Vt tile [128 d][64 keys]
#pragma unroll
            for (int it = 0; it < 2; it++) {
                int c = tid + it * 512;
                int dr = c >> 3, ck = (c & 7) * 8;
                *(float4*)(&sVt[dr][ck]) =
                    *(const float4*)(vg + (size_t)dr * SS + kbase + ck);
            }
            __syncthreads();

            // ---- QK^T: 16 q-rows x 64 keys per wave ----
            f4v sc[4];
#pragma unroll
            for (int nt = 0; nt < 4; nt++) {
                f4v a = {0.f, 0.f, 0.f, 0.f};
#pragma unroll
                for (int kc = 0; kc < 4; kc++) {
                    s8v bfrag = *(const s8v*)(&sK[nt * 16 + l15][kc * 32 + quad * 8]);
                    a = __builtin_amdgcn_mfma_f32_16x16x32_bf16(qf[kc], bfrag, a, 0, 0, 0);
                }
                sc[nt] = a;
            }
            // ---- mask + exp (no max), accumulate per-lane partial sums ----
#pragma unroll
            for (int nt = 0; nt < 4; nt++) {
                int kcol = kbase + nt * 16 + l15;
#pragma unroll
                for (int r = 0; r < 4; r++) {
                    float pv = (kcol > qgrow[r]) ? 0.f : __expf(sc[nt][r]);
                    sc[nt][r] = pv;
                    lp[r] += pv;
                }
            }
            // ---- P: C-layout -> A-layout via per-wave LDS ----
#pragma unroll
            for (int nt = 0; nt < 4; nt++)
#pragma unroll
                for (int r = 0; r < 4; r++)
                    sP[wave][quad * 4 + r][nt * 16 + l15] = __float2bfloat16(sc[nt][r]);
            asm volatile("s_waitcnt lgkmcnt(0)" ::: "memory");
            s8v pa[2];
#pragma unroll
            for (int kc = 0; kc < 2; kc++)
                pa[kc] = *(const s8v*)(&sP[wave][l15][kc * 32 + quad * 8]);
            // ---- PV ----
#pragma unroll
            for (int dt = 0; dt < 8; dt++)
#pragma unroll
                for (int kc = 0; kc < 2; kc++) {
                    s8v vb = *(const s8v*)(&sVt[dt * 16 + l15][kc * 32 + quad * 8]);
                    o[dt] = __builtin_amdgcn_mfma_f32_16x16x32_bf16(pa[kc], vb, o[dt], 0, 0, 0);
                }
        }
        // ---- final row-sum reduce (over l15) + epilogue ----
#pragma unroll
        for (int off = 1; off < 16; off <<= 1)
#pragma unroll
            for (int r = 0; r < 4; r++) lp[r] += __shfl_xor(lp[r], off, 64);
#pragma unroll
        for (int r = 0; r < 4; r++) {
            float inv = 1.0f / lp[r];
            int sg = qgrow[r];
#pragma unroll
            for (int dt = 0; dt < 8; dt++) {
                int d = dt * 16 + l15;
                out[(((size_t)(b * SS + sg)) * NH + h) * HD + d] =
                    __float2bfloat16(o[dt][r] * inv);
            }
        }
    }
}

extern "C" void kernel_launch(void* const* d_in, const int* in_sizes, int n_in,
                              void* d_out, int out_size, void* d_ws, size_t ws_size,
                              hipStream_t stream) {
    const float* hidden = (const float*)d_in[0];
    const int* positions = (const int*)d_in[1];
    const float* wqkv = (const float*)d_in[2];
    const float* qnw = (const float*)d_in[3];
    const float* knw = (const float*)d_in[4];
    const float* wo = (const float*)d_in[5];
    float* out = (float*)d_out;

    char* ws = (char*)d_ws;
    bf16* hid_bf = (bf16*)ws;                                   // 33.5 MB
    bf16* wbuf   = (bf16*)(ws + 33554432);                      // 50.3 MB (wqkv, then wo)
    bf16* qkv    = (bf16*)(ws + 33554432 + 50331648);           // 50.3 MB (later reused as attn out)
    bf16* qb     = (bf16*)(ws + 33554432 + 50331648 + 50331648);        // 33.5 MB
    bf16* kb     = (bf16*)(ws + 33554432 + 50331648 + 50331648 + 33554432);          // 8.4 MB
    bf16* vtb    = (bf16*)(ws + 33554432 + 50331648 + 50331648 + 33554432 + 8388608);// 8.4 MB
    bf16* attn   = qkv;  // reuse (attention only reads qb/kb/vtb)

    // 1. convert hidden + wqkv to bf16
    conv_kernel<<<2097152 / 256, 256, 0, stream>>>(hidden, hid_bf, 2097152);
    conv_kernel<<<3145728 / 256, 256, 0, stream>>>(wqkv, wbuf, 3145728);
    // 2. QKV GEMM: [4096,4096] x [6144,4096]^T -> bf16 [4096,6144]  (256^2 deep-prefetch)
    gemm_bt256<bf16><<<dim3(16, 24), 512, 0, stream>>>(hid_bf, wbuf, qkv, MM, QKVO, HH);
    // 3. RMSNorm + RoPE (q scaled by 1/sqrt(128))
    norm_rope_kernel<<<dim3(4096, 40), 128, 0, stream>>>(qkv, positions, qnw, knw, qb, kb);
    // 4. V transpose
    vtrans_kernel<<<dim3(64, 4, 16), dim3(32, 8), 0, stream>>>(qkv, vtb);
    // 5. causal flash attention (BQ=128, work-balanced q-tile pairing)
    attn_kernel<<<dim3(8, 32, 2), 512, 0, stream>>>(qb, kb, vtb, attn);
    // 6. convert wo, WO GEMM -> f32 output  (256^2 deep-prefetch)
    conv_kernel<<<2097152 / 256, 256, 0, stream>>>(wo, wbuf, 2097152);
    gemm_bt256<float><<<dim3(16, 16), 512, 0, stream>>>(attn, wbuf, out, MM, HH, HH);
}

// Round 4
// 771.901 us; speedup vs baseline: 1.0256x; 1.0256x over previous
//
#include <hip/hip_runtime.h>
#include <hip/hip_bf16.h>
#include <cstdint>
#include <cstddef>

typedef __hip_bfloat16 bf16;
typedef __attribute__((ext_vector_type(8))) short s8v;   // 8 bf16 (4 VGPRs) MFMA A/B frag
typedef __attribute__((ext_vector_type(4))) float f4v;   // MFMA C/D frag

#define NH 32
#define NKV 8
#define HD 128
#define BB 2
#define SS 2048
#define HH 4096
#define QKVO 6144
#define MM 4096

// ---------- async global->LDS (16B per lane) ----------
__device__ __forceinline__ void gld_lds16(const void* g, void* l) {
    __builtin_amdgcn_global_load_lds(
        (const __attribute__((address_space(1))) void*)g,
        (__attribute__((address_space(3))) void*)l, 16, 0, 0);
}

#define MFMA_BF16(a, b, c) __builtin_amdgcn_mfma_f32_16x16x32_bf16((a), (b), (c), 0, 0, 0)

// ---------- f32 -> bf16 convert, 8 elems/thread ----------
struct alignas(16) bf16x8s { bf16 v[8]; };
__global__ __launch_bounds__(256) void conv_kernel(const float* __restrict__ in,
                                                   bf16* __restrict__ out, int n8) {
    int i = blockIdx.x * 256 + threadIdx.x;
    if (i >= n8) return;
    const float4* in4 = (const float4*)in;
    float4 a = in4[i * 2];
    float4 b = in4[i * 2 + 1];
    bf16x8s p;
    p.v[0] = __float2bfloat16(a.x); p.v[1] = __float2bfloat16(a.y);
    p.v[2] = __float2bfloat16(a.z); p.v[3] = __float2bfloat16(a.w);
    p.v[4] = __float2bfloat16(b.x); p.v[5] = __float2bfloat16(b.y);
    p.v[6] = __float2bfloat16(b.z); p.v[7] = __float2bfloat16(b.w);
    *(bf16x8s*)(out + (size_t)i * 8) = p;
}

// =====================================================================
// 256x256-tile GEMM, BK=32, ring-4 LDS, ONE barrier per K-tile.
// Rationale (R2 post-mortem): the 8-phase structure serialized the LDS
// pipe (192 ds_read_b128/CU/K-tile ~ 2300cy) against the MFMA pipe
// (512 MFMA/CU/K-tile ~ 2480cy) via block-wide {barrier,lgkm0,MFMA,
// barrier} lockstep -> 6500cy/tile, MfmaUtil 33%. Ring-4 removes all
// intra-tile barriers: tile t reads slot[t&3]; tile t stages slot
// [(t+3)&3], whose readers (tile t-1) drained via their own lgkm(0)
// BEFORE the end-of-(t-1) barrier -> staging is race-free with no
// mid-tile sync. Waves stagger between barriers, so one wave's MFMA
// overlaps another's LDS drain: per-tile -> max(LDS,MFMA), not sum.
// Per K-tile per wave: 12 ds_read_b128 (a[8],b[4]) + 4 global_load_lds
// + lgkm(0) + 32 MFMA + counted vmcnt(8) + s_barrier.
// vmcnt ledger (4 stage-loads/wave/tile, FIFO): after issue at tile t,
// outstanding = {->t+1, ->t+2, ->t+3} = 12; vmcnt(8) drains ->t+1
// exactly (issued 3 tiles = ~4500cy earlier -> never stalls).
// Swizzle (T2, rule #21): row stride 64B = 4x16B slots; read position
// = slot ^ (row&3); stage source pre-swizzled the same way; linear
// gld_lds dest. 64 lanes spread uniformly: 8 accesses/bank (b128 floor).
// =====================================================================
__device__ __forceinline__ void stageT(const bf16* __restrict__ g, int ldg, int kt,
                                       int r0, char* lslot, int lane) {
    // stage 16 rows [r0,r0+16) x 32 cols (1 KiB) into ring slot, linear dest
    int sub = lane >> 2;                       // 0..15
    int row = r0 + sub;
    int cs = (lane & 3) ^ (sub & 3);           // inverse swizzle on source
    gld_lds16(g + (size_t)row * ldg + kt * 32 + cs * 8,
              lslot + r0 * 64 + lane * 16);
}

template <typename OutT>
__global__ __launch_bounds__(512, 2) void gemm_bt256(const bf16* __restrict__ A,
                                                     const bf16* __restrict__ Bm,
                                                     OutT* __restrict__ C,
                                                     int M, int N, int K) {
    __shared__ bf16 sA[4][256 * 32];           // 64 KiB ring
    __shared__ bf16 sB[4][256 * 32];           // 64 KiB ring
    const int tid = threadIdx.x;
    const int lane = tid & 63;
    const int wave = tid >> 6;                 // 0..7
    const int l15 = lane & 15, quad = lane >> 4;
    const int wm = wave >> 2;                  // 0..1 -> 128 M-rows each
    const int wn = wave & 3;                   // 0..3 -> 64 N-cols each

    // XCD-aware block swizzle (nwg % 8 == 0 for both call sites)
    const int nbn = N >> 8;
    const int nwg = (M >> 8) * nbn;
    const int orig = blockIdx.y * gridDim.x + blockIdx.x;
    const int cpx = nwg >> 3;
    const int swz = (orig & 7) * cpx + (orig >> 3);
    const int bm = swz / nbn, bn = swz % nbn;

    const bf16* Ab = A + (size_t)bm * 256 * K;
    const bf16* Bb = Bm + (size_t)bn * 256 * K;
    const int NT = K >> 5;                     // K-tiles of 32 (128 here)

    // swizzled ds_read addressing: byte = row*64 + ((quad ^ (row&3))<<4)
    const int soff  = (quad ^ (l15 & 3)) << 4;
    const int raoff = (wm * 128 + l15) * 64 + soff;   // + m*1024
    const int rboff = (wn * 64 + l15) * 64 + soff;    // + n*1024
    const int sr0 = wave * 32;                 // this wave's staging rows

    f4v acc[8][4] = {};

    // ---- prologue: stage tiles 0,1,2 into slots 0,1,2 ----
#pragma unroll
    for (int u = 0; u < 3; ++u) {
        stageT(Ab, K, u, sr0,      (char*)sA[u], lane);
        stageT(Ab, K, u, sr0 + 16, (char*)sA[u], lane);
        stageT(Bb, K, u, sr0,      (char*)sB[u], lane);
        stageT(Bb, K, u, sr0 + 16, (char*)sB[u], lane);
    }
    asm volatile("s_waitcnt vmcnt(8)" ::: "memory");   // tile0 landed; 1,2 in flight
    __builtin_amdgcn_s_barrier();

    for (int t = 0; t < NT; ++t) {
        const int sl = t & 3;
        const char* pA = (const char*)sA[sl];
        const char* pB = (const char*)sB[sl];
        s8v a[8], b[4];
#pragma unroll
        for (int m = 0; m < 8; ++m) a[m] = *(const s8v*)(pA + raoff + m * 1024);
#pragma unroll
        for (int n = 0; n < 4; ++n) b[n] = *(const s8v*)(pB + rboff + n * 1024);
        if (t + 3 < NT) {                      // stage tile t+3 -> slot (t+3)&3
            const int kt = t + 3, ds = kt & 3;
            stageT(Ab, K, kt, sr0,      (char*)sA[ds], lane);
            stageT(Ab, K, kt, sr0 + 16, (char*)sA[ds], lane);
            stageT(Bb, K, kt, sr0,      (char*)sB[ds], lane);
            stageT(Bb, K, kt, sr0 + 16, (char*)sB[ds], lane);
        }
        asm volatile("s_waitcnt lgkmcnt(0)" ::: "memory");
        __builtin_amdgcn_sched_barrier(0);     // rule #18: pin MFMA below drain
        __builtin_amdgcn_s_setprio(1);
#pragma unroll
        for (int m = 0; m < 8; ++m)
#pragma unroll
            for (int n = 0; n < 4; ++n)
                acc[m][n] = MFMA_BF16(a[m], b[n], acc[m][n]);
        __builtin_amdgcn_s_setprio(0);
        // counted drain: ensure slot[(t+1)&3] landed block-wide after barrier
        if (t + 3 < NT)      { asm volatile("s_waitcnt vmcnt(8)" ::: "memory"); }
        else if (t + 3 == NT){ asm volatile("s_waitcnt vmcnt(4)" ::: "memory"); }
        else if (t + 2 == NT){ asm volatile("s_waitcnt vmcnt(0)" ::: "memory"); }
        if (t + 1 < NT) __builtin_amdgcn_s_barrier();
    }

    // ---- epilogue ----
#pragma unroll
    for (int m = 0; m < 8; ++m)
#pragma unroll
        for (int n = 0; n < 4; ++n) {
            int r0 = bm * 256 + wm * 128 + m * 16 + quad * 4;
            int c0 = bn * 256 + wn * 64 + n * 16 + l15;
#pragma unroll
            for (int r = 0; r < 4; ++r) {
                float v = acc[m][n][r];
                if constexpr (sizeof(OutT) == 2)
                    C[(size_t)(r0 + r) * N + c0] = (OutT)__float2bfloat16(v);
                else
                    C[(size_t)(r0 + r) * N + c0] = (OutT)v;
            }
        }
}

// ---------- RMSNorm + RoPE for Q and K heads ----------
__global__ __launch_bounds__(128) void norm_rope_kernel(
    const bf16* __restrict__ qkv, const int* __restrict__ positions,
    const float* __restrict__ qw, const float* __restrict__ kw,
    bf16* __restrict__ qb, bf16* __restrict__ kb) {
    int rowid = blockIdx.x;   // 0..4095 (b*2048+s)
    int head = blockIdx.y;    // 0..39   (0..31 q, 32..39 k)
    int d = threadIdx.x;      // 0..127
    int b = rowid >> 11, s = rowid & 2047;
    bool isq = head < NH;
    int col = isq ? head * HD + d : NH * HD + (head - NH) * HD + d;
    float x = __bfloat162float(qkv[(size_t)rowid * QKVO + col]);

    __shared__ float sv[128];
    __shared__ float partial[2];
    float ss = x * x;
#pragma unroll
    for (int off = 32; off; off >>= 1) ss += __shfl_xor(ss, off, 64);
    if ((threadIdx.x & 63) == 0) partial[threadIdx.x >> 6] = ss;
    __syncthreads();
    float var = (partial[0] + partial[1]) * (1.0f / 128.0f);
    float w = isq ? qw[d] : kw[d];
    float xn = x * rsqrtf(var + 1e-6f) * w;
    sv[d] = xn;
    __syncthreads();

    float pos = (float)positions[s];
    float o;
    // inv_freq = 10000^(-i/64) = exp2(-i * log2(10000)/64), log2(10000)=13.2877123795
    if (d < 64) {
        float ang = pos * exp2f(-(float)d * 0.20762051f);
        float c, si; __sincosf(ang, &si, &c);
        o = xn * c - sv[d + 64] * si;
    } else {
        int i = d - 64;
        float ang = pos * exp2f(-(float)i * 0.20762051f);
        float c, si; __sincosf(ang, &si, &c);
        o = xn * c + sv[i] * si;
    }
    if (isq) o *= 0.08838834764831845f;  // 1/sqrt(128) folded into Q
    size_t oidx;
    if (isq) oidx = (((size_t)(b * NH + head) * SS + s) * HD + d);
    else     oidx = (((size_t)(b * NKV + (head - NH)) * SS + s) * HD + d);
    (isq ? qb : kb)[oidx] = __float2bfloat16(o);
}

// ---------- V transpose: qkv v-part [s][d] -> vt [b][kv][d][s] ----------
__global__ __launch_bounds__(256) void vtrans_kernel(const bf16* __restrict__ qkv,
                                                     bf16* __restrict__ vt) {
    int bh = blockIdx.z;           // b*8+hv
    int s0 = blockIdx.x * 32, d0 = blockIdx.y * 32;
    int b = bh >> 3, hv = bh & 7;
    __shared__ bf16 tile[32][33];
    int tx = threadIdx.x, ty = threadIdx.y;
    size_t colbase = (size_t)(NH + NKV) * HD + hv * HD + d0;  // v starts at col 5120
    for (int i = 0; i < 4; i++) {
        int s = s0 + ty + i * 8;
        tile[ty + i * 8][tx] = qkv[(size_t)(b * SS + s) * QKVO + colbase + tx];
    }
    __syncthreads();
    for (int i = 0; i < 4; i++) {
        int d = d0 + ty + i * 8;
        vt[((size_t)(bh * HD + d)) * SS + s0 + tx] = tile[tx][ty + i * 8];
    }
}

// ---------- causal flash attention ----------
// BQ=128, BK=64, 8 waves. No-max softmax: post-RMSNorm |score| <= sqrt(128),
// so exp(score) <= 8.2e4 and sum <= 1.7e8 -- safe in f32 without max
// subtraction. Work-balanced: block pi handles q-tiles {pi, 15-pi}.
__global__ __launch_bounds__(512, 4) void attn_kernel(
    const bf16* __restrict__ q, const bf16* __restrict__ k,
    const bf16* __restrict__ vt, bf16* __restrict__ out) {
    int pi = blockIdx.x;   // 0..7
    int h = blockIdx.y;
    int b = blockIdx.z;
    int hk = h >> 2;  // 4 q heads per kv head
    int tid = threadIdx.x, lane = tid & 63, wave = tid >> 6;  // wave 0..7
    int l15 = lane & 15, quad = lane >> 4;

    __shared__ bf16 sK[64][136];     // 272B stride: 2-way bank aliasing (free)
    __shared__ bf16 sVt[128][72];    // 144B stride
    __shared__ bf16 sP[8][16][72];   // per-wave P scratch

    const bf16* qg = q + ((size_t)(b * NH + h) * SS) * HD;
    const bf16* kg = k + ((size_t)(b * NKV + hk) * SS) * HD;
    const bf16* vg = vt + ((size_t)(b * NKV + hk) * HD) * SS;

    for (int half = 0; half < 2; half++) {
        int qt = half ? (15 - pi) : pi;
        int q0 = qt * 128;
        int qrow = q0 + wave * 16 + l15;
        s8v qf[4];
#pragma unroll
        for (int kc = 0; kc < 4; kc++)
            qf[kc] = *(const s8v*)(qg + (size_t)qrow * HD + kc * 32 + quad * 8);

        f4v o[8] = {};
        float lp[4] = {0.f, 0.f, 0.f, 0.f};   // per-lane partial row sums
        int qgrow[4];
#pragma unroll
        for (int r = 0; r < 4; r++) qgrow[r] = q0 + wave * 16 + quad * 4 + r;

        int nkt = 2 * qt + 2;  // causal: keys 0 .. q0+127, BK=64
        for (int kt = 0; kt < nkt; kt++) {
            int kbase = kt * 64;
            __syncthreads();  // prev iter's LDS reads done -> safe to restage
            // stage K tile [64 keys][128 d]
#pragma unroll
            for (int it = 0; it < 2; it++) {
                int c = tid + it * 512;
                int r = c >> 4, c8 = (c & 15) * 8;
                *(float4*)(&sK[r][c8]) =
                    *(const float4*)(kg + (size_t)(kbase + r) * HD + c8);
            }
            // stage Vt tile [128 d][64 keys]
#pragma unroll
            for (int it = 0; it < 2; it++) {
                int c = tid + it * 512;
                int dr = c >> 3, ck = (c & 7) * 8;
                *(float4*)(&sVt[dr][ck]) =
                    *(const float4*)(vg + (size_t)dr * SS + kbase + ck);
            }
            __syncthreads();

            // ---- QK^T: 16 q-rows x 64 keys per wave ----
            f4v sc[4];
#pragma unroll
            for (int nt = 0; nt < 4; nt++) {
                f4v a = {0.f, 0.f, 0.f, 0.f};
#pragma unroll
                for (int kc = 0; kc < 4; kc++) {
                    s8v bfrag = *(const s8v*)(&sK[nt * 16 + l15][kc * 32 + quad * 8]);
                    a = __builtin_amdgcn_mfma_f32_16x16x32_bf16(qf[kc], bfrag, a, 0, 0, 0);
                }
                sc[nt] = a;
            }
            // ---- mask + exp (no max), accumulate per-lane partial sums ----
#pragma unroll
            for (int nt = 0; nt < 4; nt++) {
                int kcol = kbase + nt * 16 + l15;
#pragma unroll
                for (int r = 0; r < 4; r++) {
                    float pv = (kcol > qgrow[r]) ? 0.f : __expf(sc[nt][r]);
                    sc[nt][r] = pv;
                    lp[r] += pv;
                }
            }
            // ---- P: C-layout -> A-layout via per-wave LDS ----
#pragma unroll
            for (int nt = 0; nt < 4; nt++)
#pragma unroll
                for (int r = 0; r < 4; r++)
                    sP[wave][quad * 4 + r][nt * 16 + l15] = __float2bfloat16(sc[nt][r]);
            asm volatile("s_waitcnt lgkmcnt(0)" ::: "memory");
            s8v pa[2];
#pragma unroll
            for (int kc = 0; kc < 2; kc++)
                pa[kc] = *(const s8v*)(&sP[wave][l15][kc * 32 + quad * 8]);
            // ---- PV ----
#pragma unroll
            for (int dt = 0; dt < 8; dt++)
#pragma unroll
                for (int kc = 0; kc < 2; kc++) {
                    s8v vb = *(const s8v*)(&sVt[dt * 16 + l15][kc * 32 + quad * 8]);
                    o[dt] = __builtin_amdgcn_mfma_f32_16x16x32_bf16(pa[kc], vb, o[dt], 0, 0, 0);
                }
        }
        // ---- final row-sum reduce (over l15) + epilogue ----
#pragma unroll
        for (int off = 1; off < 16; off <<= 1)
#pragma unroll
            for (int r = 0; r < 4; r++) lp[r] += __shfl_xor(lp[r], off, 64);
#pragma unroll
        for (int r = 0; r < 4; r++) {
            float inv = 1.0f / lp[r];
            int sg = qgrow[r];
#pragma unroll
            for (int dt = 0; dt < 8; dt++) {
                int d = dt * 16 + l15;
                out[(((size_t)(b * SS + sg)) * NH + h) * HD + d] =
                    __float2bfloat16(o[dt][r] * inv);
            }
        }
    }
}

extern "C" void kernel_launch(void* const* d_in, const int* in_sizes, int n_in,
                              void* d_out, int out_size, void* d_ws, size_t ws_size,
                              hipStream_t stream) {
    const float* hidden = (const float*)d_in[0];
    const int* positions = (const int*)d_in[1];
    const float* wqkv = (const float*)d_in[2];
    const float* qnw = (const float*)d_in[3];
    const float* knw = (const float*)d_in[4];
    const float* wo = (const float*)d_in[5];
    float* out = (float*)d_out;

    char* ws = (char*)d_ws;
    bf16* hid_bf = (bf16*)ws;                                   // 33.5 MB
    bf16* wbuf   = (bf16*)(ws + 33554432);                      // 50.3 MB (wqkv, then wo)
    bf16* qkv    = (bf16*)(ws + 33554432 + 50331648);           // 50.3 MB (later reused as attn out)
    bf16* qb     = (bf16*)(ws + 33554432 + 50331648 + 50331648);        // 33.5 MB
    bf16* kb     = (bf16*)(ws + 33554432 + 50331648 + 50331648 + 33554432);          // 8.4 MB
    bf16* vtb    = (bf16*)(ws + 33554432 + 50331648 + 50331648 + 33554432 + 8388608);// 8.4 MB
    bf16* attn   = qkv;  // reuse (attention only reads qb/kb/vtb)

    // 1. convert hidden + wqkv to bf16
    conv_kernel<<<2097152 / 256, 256, 0, stream>>>(hidden, hid_bf, 2097152);
    conv_kernel<<<3145728 / 256, 256, 0, stream>>>(wqkv, wbuf, 3145728);
    // 2. QKV GEMM: [4096,4096] x [6144,4096]^T -> bf16 [4096,6144]  (ring-4, BK=32)
    gemm_bt256<bf16><<<dim3(16, 24), 512, 0, stream>>>(hid_bf, wbuf, qkv, MM, QKVO, HH);
    // 3. RMSNorm + RoPE (q scaled by 1/sqrt(128))
    norm_rope_kernel<<<dim3(4096, 40), 128, 0, stream>>>(qkv, positions, qnw, knw, qb, kb);
    // 4. V transpose
    vtrans_kernel<<<dim3(64, 4, 16), dim3(32, 8), 0, stream>>>(qkv, vtb);
    // 5. causal flash attention (BQ=128, work-balanced q-tile pairing)
    attn_kernel<<<dim3(8, 32, 2), 512, 0, stream>>>(qb, kb, vtb, attn);
    // 6. convert wo, WO GEMM -> f32 output  (ring-4, BK=32)
    conv_kernel<<<2097152 / 256, 256, 0, stream>>>(wo, wbuf, 2097152);
    gemm_bt256<float><<<dim3(16, 16), 512, 0, stream>>>(attn, wbuf, out, MM, HH, HH);
}